// Round 13
// baseline (155.128 us; speedup 1.0000x reference)
//
#include <hip/hip_runtime.h>
#include <math.h>

// Problem constants (B, S, E, WIN) = (8, 2048, 512, 11)
#define B_    8
#define S_    2048
#define E_    512
#define WIN_  11
#define WW    5              // WIN/2
#define F4C   1408           // float4 per W row (5632/4)
#define E4C   128            // float4 per x row (512/4)
#define G_    2              // s-values per block
#define NBLK  (S_ / G_)      // 1024 blocks
#define PSTR  (B_ * WIN_)    // 88 gate logits per s

// ---- DPP wave-sum: 6 VALU ops, zero DS-pipe traffic. Full sum -> lane 63.
template <int CTRL, int RMASK>
__device__ __forceinline__ float dpp_add(float v) {
    int sh = __builtin_amdgcn_update_dpp(0, __float_as_int(v),
                                         CTRL, RMASK, 0xF, true);
    return v + __int_as_float(sh);
}
__device__ __forceinline__ float wave_sum63(float v) {
    v = dpp_add<0x111, 0xF>(v);   // row_shr:1
    v = dpp_add<0x112, 0xF>(v);   // row_shr:2
    v = dpp_add<0x114, 0xF>(v);   // row_shr:4
    v = dpp_add<0x118, 0xF>(v);   // row_shr:8
    v = dpp_add<0x142, 0xA>(v);   // row_bcast:15
    v = dpp_add<0x143, 0xC>(v);   // row_bcast:31 -> lane 63 = full sum
    return v;
}

__device__ __forceinline__ float tanh_fast(float v) {
    const float e = __expf(v + v);
    return 1.f - 2.f / (e + 1.f);
}

// ---------------------------------------------------------------------------
// R13: G=2 s-values per block — x-stage amortization.
// Traffic model (R12 post-mortem): every config since R10 is pinned at the
// ~6.1-6.3 TB/s TOTAL vector-traffic ceiling (m13), so the lever is BYTES.
// Iterating physical rows r = s0-5 .. s0+6, x[:, r, :] is staged ONCE and
// consumed by BOTH s0 (wp0 = r-s0+5) and s1 (wp1 = wp0-1):
//   x staged: 360 MB -> 197 MB chip-wide; total vector bytes 867 -> ~770 MB.
// Chunk = (r, half-e): stage x half-row (8 KB) + W[s0][wp0] half (11 KB,
// if v0) + W[s1][wp1] half (11 KB, if v1) via global_load_lds(16B)
// -> __syncthreads -> ds_read + FMA into acc[2][8][3] -> __syncthreads.
// (R10's simple drain structure — beat counted-vmcnt pipelining twice.)
// Wave g owns w-rows 3g..3g+2 for all 8 batches, both s. LDS 30.8 KB.
// ---------------------------------------------------------------------------
__global__ __launch_bounds__(256)
void win_attn_fused(const float* __restrict__ x,
                    const float* __restrict__ W,
                    const float* __restrict__ bias,
                    float* __restrict__ out)
{
    const int bid  = blockIdx.x;
    const int sb   = (bid & 7) * (NBLK / 8) + (bid >> 3);  // bijective XCD swizzle
    const int s0   = sb * G_;
    const int tid  = threadIdx.x;
    const int wid  = tid >> 6;      // wave 0..3
    const int lane = tid & 63;

    const float4* __restrict__ X4  = reinterpret_cast<const float4*>(x);
    const float4* __restrict__ Ws0 = reinterpret_cast<const float4*>(W)
                                     + (size_t)s0 * (WIN_ * F4C);
    const float4* __restrict__ Ws1 = Ws0 + (WIN_ * F4C);

    __shared__ float4 xb[B_ * 64];    // 8 KB: [b][64] half-row
    __shared__ float4 Wb0[WIN_ * 64]; // 11 KB: [w][64] for s0's current wp
    __shared__ float4 Wb1[WIN_ * 64]; // 11 KB: [w][64] for s1's current wp
    __shared__ float gates[G_ * PSTR];

    const int w0   = wid * 3;                  // first w-row of this wave
    const int wcnt = (wid == 3) ? 2 : 3;       // wave 3 owns rows 9,10

    float acc[G_][B_][3];
    #pragma unroll
    for (int si = 0; si < G_; ++si)
        #pragma unroll
        for (int b = 0; b < B_; ++b)
            #pragma unroll
            for (int j = 0; j < 3; ++j) acc[si][b][j] = 0.f;

    #pragma unroll 1
    for (int r = s0 - WW; r <= s0 + WW + 1; ++r) {
        if (r < 0 || r >= S_) continue;        // block-uniform (pad rows = 0)
        const int wp0 = r - s0 + WW;           // 0..11  (valid if <= 10)
        const int wp1 = wp0 - 1;               // -1..10 (valid if >= 0)
        const bool v0 = (wp0 <= WIN_ - 1);
        const bool v1 = (wp1 >= 0);

        #pragma unroll
        for (int h = 0; h < 2; ++h) {
            // ---- stage: x half-row (512 f4) + up to 2 W half-chunks (704 f4)
            #pragma unroll
            for (int j = 0; j < 2; ++j) {
                const int n  = j * 256 + tid;       // [0,512)
                const int b  = n >> 6;
                const int el = n & 63;
                const float4* src = X4 + ((size_t)b * S_ + r) * E4C + h * 64 + el;
                __builtin_amdgcn_global_load_lds(
                    (const __attribute__((address_space(1))) void*)src,
                    (__attribute__((address_space(3))) void*)&xb[n],
                    16, 0, 0);
            }
            if (v0) {
                #pragma unroll
                for (int j = 0; j < 3; ++j) {
                    const int m = j * 256 + tid;    // [0,768)
                    if (j < 2 || tid < 192) {       // m < 704, wave-uniform
                        const int w  = m >> 6;
                        const int el = m & 63;
                        const float4* src = Ws0 + (size_t)w * F4C
                                            + wp0 * E4C + h * 64 + el;
                        __builtin_amdgcn_global_load_lds(
                            (const __attribute__((address_space(1))) void*)src,
                            (__attribute__((address_space(3))) void*)&Wb0[m],
                            16, 0, 0);
                    }
                }
            }
            if (v1) {
                #pragma unroll
                for (int j = 0; j < 3; ++j) {
                    const int m = j * 256 + tid;
                    if (j < 2 || tid < 192) {
                        const int w  = m >> 6;
                        const int el = m & 63;
                        const float4* src = Ws1 + (size_t)w * F4C
                                            + wp1 * E4C + h * 64 + el;
                        __builtin_amdgcn_global_load_lds(
                            (const __attribute__((address_space(1))) void*)src,
                            (__attribute__((address_space(3))) void*)&Wb1[m],
                            16, 0, 0);
                    }
                }
            }
            __syncthreads();   // staging complete (vmcnt drain)

            // ---- compute from LDS ----
            float4 xv[B_];
            #pragma unroll
            for (int b = 0; b < B_; ++b) xv[b] = xb[b * 64 + lane];

            if (v0) {
                float4 wv[3];
                #pragma unroll
                for (int j = 0; j < 3; ++j)
                    if (j < wcnt) wv[j] = Wb0[(w0 + j) * 64 + lane];
                #pragma unroll
                for (int b = 0; b < B_; ++b)
                    #pragma unroll
                    for (int j = 0; j < 3; ++j)
                        if (j < wcnt) {
                            float a = acc[0][b][j];
                            a = fmaf(xv[b].x, wv[j].x, a);
                            a = fmaf(xv[b].y, wv[j].y, a);
                            a = fmaf(xv[b].z, wv[j].z, a);
                            a = fmaf(xv[b].w, wv[j].w, a);
                            acc[0][b][j] = a;
                        }
            }
            if (v1) {
                float4 wv[3];
                #pragma unroll
                for (int j = 0; j < 3; ++j)
                    if (j < wcnt) wv[j] = Wb1[(w0 + j) * 64 + lane];
                #pragma unroll
                for (int b = 0; b < B_; ++b)
                    #pragma unroll
                    for (int j = 0; j < 3; ++j)
                        if (j < wcnt) {
                            float a = acc[1][b][j];
                            a = fmaf(xv[b].x, wv[j].x, a);
                            a = fmaf(xv[b].y, wv[j].y, a);
                            a = fmaf(xv[b].z, wv[j].z, a);
                            a = fmaf(xv[b].w, wv[j].w, a);
                            acc[1][b][j] = a;
                        }
            }
            __syncthreads();   // WAR before next stage overwrites buffers
        }
    }

    // ---- DPP reduce (VALU only) -> gate logits -> sigmoid ----
    #pragma unroll
    for (int si = 0; si < G_; ++si)
        #pragma unroll
        for (int b = 0; b < B_; ++b)
            #pragma unroll
            for (int j = 0; j < 3; ++j)
                if (j < wcnt) acc[si][b][j] = wave_sum63(acc[si][b][j]);

    if (lane == 63) {
        #pragma unroll
        for (int si = 0; si < G_; ++si)
            #pragma unroll
            for (int b = 0; b < B_; ++b)
                #pragma unroll
                for (int j = 0; j < 3; ++j)
                    if (j < wcnt)
                        gates[si * PSTR + b * WIN_ + w0 + j] = acc[si][b][j];
    }
    __syncthreads();

    if (tid < G_ * PSTR) {
        const int si = tid / PSTR;
        const int w  = tid % WIN_;
        const float v = gates[tid] + bias[(s0 + si) * WIN_ + w];
        gates[tid] = 1.f / (1.f + __expf(-v));
    }
    __syncthreads();

    // ---- score + tanh (x rows L2-hot from the chunk loop) ----
    float4* __restrict__ OUT4 = reinterpret_cast<float4*>(out);
    #pragma unroll
    for (int si = 0; si < G_; ++si) {
        const int s = s0 + si;
        #pragma unroll
        for (int it = 0; it < 4; ++it) {
            const int i  = tid + (it << 8);   // 0..1023 -> (b, e4)
            const int b  = i >> 7;
            const int e4 = i & 127;
            float4 sc = make_float4(0.f, 0.f, 0.f, 0.f);
            #pragma unroll
            for (int w = 0; w < WIN_; ++w) {
                const int rr = s - WW + w;
                if (rr >= 0 && rr < S_) {
                    const float g   = gates[si * PSTR + b * WIN_ + w];
                    const float4 xv = X4[((size_t)b * S_ + rr) * E4C + e4];
                    sc.x = fmaf(g, xv.x, sc.x);
                    sc.y = fmaf(g, xv.y, sc.y);
                    sc.z = fmaf(g, xv.z, sc.z);
                    sc.w = fmaf(g, xv.w, sc.w);
                }
            }
            float4 o;
            o.x = tanh_fast(sc.x);
            o.y = tanh_fast(sc.y);
            o.z = tanh_fast(sc.z);
            o.w = tanh_fast(sc.w);
            OUT4[((size_t)b * S_ + s) * E4C + e4] = o;
        }
    }
}

extern "C" void kernel_launch(void* const* d_in, const int* in_sizes, int n_in,
                              void* d_out, int out_size, void* d_ws, size_t ws_size,
                              hipStream_t stream)
{
    const float* x    = (const float*)d_in[0];
    const float* W    = (const float*)d_in[1];
    const float* bias = (const float*)d_in[2];
    float* out        = (float*)d_out;

    win_attn_fused<<<dim3(NBLK), dim3(256), 0, stream>>>(x, W, bias, out);
}

// Round 14
// 132.635 us; speedup vs baseline: 1.1696x; 1.1696x over previous
//
#include <hip/hip_runtime.h>
#include <math.h>

// Problem constants (B, S, E, WIN) = (8, 2048, 512, 11)
#define B_    8
#define S_    2048
#define E_    512
#define WIN_  11
#define WW    5              // WIN/2
#define F4C   1408           // float4 per W row (5632/4)
#define E4C   128            // float4 per x row (512/4)
#define PSTR  (B_ * WIN_)    // 88 gate logits per s

// ---- DPP wave-sum: 6 VALU ops, zero DS-pipe traffic. Full sum -> lane 63.
template <int CTRL, int RMASK>
__device__ __forceinline__ float dpp_add(float v) {
    int sh = __builtin_amdgcn_update_dpp(0, __float_as_int(v),
                                         CTRL, RMASK, 0xF, true);
    return v + __int_as_float(sh);
}
__device__ __forceinline__ float wave_sum63(float v) {
    v = dpp_add<0x111, 0xF>(v);   // row_shr:1
    v = dpp_add<0x112, 0xF>(v);   // row_shr:2
    v = dpp_add<0x114, 0xF>(v);   // row_shr:4
    v = dpp_add<0x118, 0xF>(v);   // row_shr:8
    v = dpp_add<0x142, 0xA>(v);   // row_bcast:15
    v = dpp_add<0x143, 0xC>(v);   // row_bcast:31 -> lane 63 = full sum
    return v;
}

__device__ __forceinline__ float tanh_fast(float v) {
    const float e = __expf(v + v);
    return 1.f - 2.f / (e + 1.f);
}

// ---------------------------------------------------------------------------
// R14 = R10 (best, 143 us) + ONE change: W staging loads are NON-TEMPORAL
// (aux=2 = NT bit on gfx940+). Theory: the 507 MB one-shot W stream was
// thrashing x out of per-XCD L2 (4 MB; W streams ~4.4 MB through it within
// one x-row reuse window) AND out of L3, so the 360 MB x-staging + 360 MB
// epilogue x reads were HBM-served — matching the observed 143 us at ~1.2 GB
// HBM. NT keeps W from polluting the caches; x (which has 11-fold reuse
// across s-blocks) stays temporal and should become L2/L3-resident.
// Everything else byte-identical to R10 to isolate the variable.
// ---------------------------------------------------------------------------
__global__ __launch_bounds__(256)
void win_attn_fused(const float* __restrict__ x,
                    const float* __restrict__ W,
                    const float* __restrict__ bias,
                    float* __restrict__ out)
{
    const int bid  = blockIdx.x;
    const int s    = (bid & 7) * (S_ / 8) + (bid >> 3);   // bijective XCD swizzle
    const int tid  = threadIdx.x;
    const int wid  = tid >> 6;      // wave 0..3
    const int lane = tid & 63;

    const float4* __restrict__ X4 = reinterpret_cast<const float4*>(x);
    const float4* __restrict__ Ws = reinterpret_cast<const float4*>(W)
                                    + (size_t)s * (WIN_ * F4C);

    __shared__ float4 Wbuf[WIN_ * E4C];   // 22.5 KB: [w][e4] for current wp
    __shared__ float4 xbuf[B_ * E4C];     // 16 KB:   [b][e4] for current row
    __shared__ float gates[PSTR];

    const int w0   = wid * 3;                  // first w-row of this wave
    const int wcnt = (wid == 3) ? 2 : 3;       // wave 3 owns rows 9,10

    float acc[B_][3];
    #pragma unroll
    for (int b = 0; b < B_; ++b)
        #pragma unroll
        for (int j = 0; j < 3; ++j) acc[b][j] = 0.f;

    const int wpLo = (s >= WW) ? 0 : (WW - s);
    const int wpHi = (WIN_ < S_ + WW - s) ? WIN_ : (S_ + WW - s);

    #pragma unroll 1
    for (int wp = wpLo; wp < wpHi; ++wp) {
        const int row = s - WW + wp;      // always valid in [wpLo, wpHi)

        // ---- stage W chunk (1408 f4, NT) + x row (1024 f4, temporal) ----
        #pragma unroll
        for (int j = 0; j < 6; ++j) {
            const int m = j * 256 + tid;          // [0,1536)
            if (j < 5 || wid < 2) {               // wave-uniform guard (m<1408)
                const int w  = m >> 7;
                const int e4 = m & 127;
                const float4* src = Ws + (size_t)w * F4C + wp * E4C + e4;
                __builtin_amdgcn_global_load_lds(
                    (const __attribute__((address_space(1))) void*)src,
                    (__attribute__((address_space(3))) void*)&Wbuf[m],
                    16, 0, 2 /* NT: stream W, don't evict x from L2/L3 */);
            }
        }
        #pragma unroll
        for (int j = 0; j < 4; ++j) {
            const int m = j * 256 + tid;          // [0,1024): b = m>>7, e4 = m&127
            const int b  = m >> 7;
            const int e4 = m & 127;
            const float4* src = X4 + ((size_t)b * S_ + row) * E4C + e4;
            __builtin_amdgcn_global_load_lds(
                (const __attribute__((address_space(1))) void*)src,
                (__attribute__((address_space(3))) void*)&xbuf[m],
                16, 0, 0);
        }
        __syncthreads();   // staging complete (vmcnt drain)

        // ---- compute: wave's 3 w-rows x all 8 batches, e-slices lane/lane+64
        float4 wv[3][2];
        #pragma unroll
        for (int j = 0; j < 3; ++j)
            if (j < wcnt) {
                wv[j][0] = Wbuf[(w0 + j) * E4C + lane];
                wv[j][1] = Wbuf[(w0 + j) * E4C + lane + 64];
            }

        #pragma unroll
        for (int half = 0; half < 2; ++half) {
            float4 xv[4][2];
            #pragma unroll
            for (int bb = 0; bb < 4; ++bb) {
                const int b = half * 4 + bb;
                xv[bb][0] = xbuf[b * E4C + lane];
                xv[bb][1] = xbuf[b * E4C + lane + 64];
            }
            #pragma unroll
            for (int bb = 0; bb < 4; ++bb) {
                const int b = half * 4 + bb;
                #pragma unroll
                for (int j = 0; j < 3; ++j)
                    if (j < wcnt) {
                        float a = acc[b][j];
                        a = fmaf(xv[bb][0].x, wv[j][0].x, a);
                        a = fmaf(xv[bb][0].y, wv[j][0].y, a);
                        a = fmaf(xv[bb][0].z, wv[j][0].z, a);
                        a = fmaf(xv[bb][0].w, wv[j][0].w, a);
                        a = fmaf(xv[bb][1].x, wv[j][1].x, a);
                        a = fmaf(xv[bb][1].y, wv[j][1].y, a);
                        a = fmaf(xv[bb][1].z, wv[j][1].z, a);
                        a = fmaf(xv[bb][1].w, wv[j][1].w, a);
                        acc[b][j] = a;
                    }
            }
        }
        __syncthreads();   // WAR: all reads done before next chunk stages
    }

    // ---- DPP reduce (VALU only) -> gate logits -> sigmoid ----
    #pragma unroll
    for (int b = 0; b < B_; ++b)
        #pragma unroll
        for (int j = 0; j < 3; ++j)
            if (j < wcnt) acc[b][j] = wave_sum63(acc[b][j]);

    if (lane == 63) {
        #pragma unroll
        for (int b = 0; b < B_; ++b)
            #pragma unroll
            for (int j = 0; j < 3; ++j)
                if (j < wcnt) gates[b * WIN_ + w0 + j] = acc[b][j];
    }
    __syncthreads();

    if (tid < PSTR) {
        const int w = tid % WIN_;
        const float v = gates[tid] + bias[s * WIN_ + w];
        gates[tid] = 1.f / (1.f + __expf(-v));
    }
    __syncthreads();

    // ---- score + tanh (x rows now L2/L3-resident thanks to NT W) ----
    float4* __restrict__ OUT4 = reinterpret_cast<float4*>(out);
    #pragma unroll
    for (int it = 0; it < 4; ++it) {
        const int i  = tid + (it << 8);   // 0..1023 -> (b, e4)
        const int b  = i >> 7;
        const int e4 = i & 127;
        float4 sc = make_float4(0.f, 0.f, 0.f, 0.f);
        #pragma unroll
        for (int w = 0; w < WIN_; ++w) {
            const int r = s - WW + w;
            if (r >= 0 && r < S_) {
                const float g   = gates[b * WIN_ + w];
                const float4 xv = X4[((size_t)b * S_ + r) * E4C + e4];
                sc.x = fmaf(g, xv.x, sc.x);
                sc.y = fmaf(g, xv.y, sc.y);
                sc.z = fmaf(g, xv.z, sc.z);
                sc.w = fmaf(g, xv.w, sc.w);
            }
        }
        float4 o;
        o.x = tanh_fast(sc.x);
        o.y = tanh_fast(sc.y);
        o.z = tanh_fast(sc.z);
        o.w = tanh_fast(sc.w);
        OUT4[((size_t)b * S_ + s) * E4C + e4] = o;
    }
}

extern "C" void kernel_launch(void* const* d_in, const int* in_sizes, int n_in,
                              void* d_out, int out_size, void* d_ws, size_t ws_size,
                              hipStream_t stream)
{
    const float* x    = (const float*)d_in[0];
    const float* W    = (const float*)d_in[1];
    const float* bias = (const float*)d_in[2];
    float* out        = (float*)d_out;

    win_attn_fused<<<dim3(S_), dim3(256), 0, stream>>>(x, W, bias, out);
}